// Round 4
// baseline (8615.891 us; speedup 1.0000x reference)
//
#include <hip/hip_runtime.h>
#include <cstdint>
#include <cstddef>

// ---------------------------------------------------------------------------
// Problem constants
// ---------------------------------------------------------------------------
#define BB 32      // batch
#define TT 512     // seq len
#define DD 512     // emb dim
#define HH 512     // lstm size
#define FOURH 2048
#define DIRS 10    // 5 stacks x {fw,bw}
#define HSZ ((size_t)DIRS * BB * HH)     // elems per h ping-pong buffer
#define LWPITCH 520                      // 512 + 8 pad (keeps 16B alignment)
#define SMEM_REC (128 * LWPITCH * 2 + 2 * 2 * 4 * 4 * 64 * 4)   // 133120 + 16384 = 149504

typedef unsigned short u16;
typedef __attribute__((ext_vector_type(8))) short short8;   // 8 x bf16 (4 VGPRs)
typedef __attribute__((ext_vector_type(4))) float f32x4;    // MFMA accum

__device__ __forceinline__ u16 f2b(float f) {
    union { float f; unsigned u; } v; v.f = f;
    unsigned u = v.u;
    u = (u + 0x7FFFu + ((u >> 16) & 1u)) >> 16;   // RNE
    return (u16)u;
}
__device__ __forceinline__ float b2f(u16 b) {
    union { unsigned u; float f; } v; v.u = ((unsigned)b) << 16;
    return v.f;
}
__device__ __forceinline__ float sigm(float x) { return 1.f / (1.f + __expf(-x)); }
__device__ __forceinline__ float tanh_(float x) { return 1.f - 2.f / (1.f + __expf(2.f * x)); }
__device__ __forceinline__ f32x4 fzero() { f32x4 z = {0.f, 0.f, 0.f, 0.f}; return z; }

// ---------------------------------------------------------------------------
// K1: x fp32 -> bf16
// ---------------------------------------------------------------------------
__global__ void k_convx(const float* __restrict__ X, u16* __restrict__ XB) {
    int i = blockIdx.x * 256 + threadIdx.x;
    if (i >= (BB * TT * DD) / 4) return;
    float4 v = ((const float4*)X)[i];
    unsigned lo = (unsigned)f2b(v.x) | ((unsigned)f2b(v.y) << 16);
    unsigned hi = (unsigned)f2b(v.z) | ((unsigned)f2b(v.w) << 16);
    uint2 o; o.x = lo; o.y = hi;
    ((uint2*)XB)[i] = o;
}

// ---------------------------------------------------------------------------
// K2: build WT[d][n][k] = W_src[s][k][n] (bf16), LDS-tiled transpose.
// ---------------------------------------------------------------------------
__global__ void k_wt(const float* __restrict__ Wf, const float* __restrict__ Wb,
                     u16* __restrict__ WT) {
    int d = blockIdx.z, s = d >> 1;
    const float* src = (d & 1) ? Wb : Wf;   // [5][1024][2048]
    __shared__ float tile[32][33];
    int tx = threadIdx.x & 31, ty = threadIdx.x >> 5;
    int kt = blockIdx.x, nt = blockIdx.y;
#pragma unroll
    for (int r = 0; r < 4; r++) {
        int k = kt * 32 + ty + r * 8, n = nt * 32 + tx;
        tile[ty + r * 8][tx] = src[((size_t)s * 1024 + k) * 2048 + n];
    }
    __syncthreads();
#pragma unroll
    for (int r = 0; r < 4; r++) {
        int n = nt * 32 + ty + r * 8, k = kt * 32 + tx;
        WT[((size_t)d * 2048 + n) * 1024 + k] = f2b(tile[tx][ty + r * 8]);
    }
}

// ---------------------------------------------------------------------------
// K3: build head weight WBT[64 c][5120 k] bf16 + bias B64[64].
// ---------------------------------------------------------------------------
__global__ void k_wbt(const float* W1, const float* W2, const float* W3, const float* W4,
                      const float* b1, const float* b2, const float* b3, const float* b4,
                      u16* __restrict__ WBT, float* __restrict__ B64) {
    int idx = blockIdx.x * 256 + threadIdx.x;
    const int off[4] = {0, 17, 26, 51};
    const int tg[4]  = {17, 9, 25, 13};
    if (idx < 64) {
        int c = idx;
        int ti = (c < 17) ? 0 : (c < 26) ? 1 : (c < 51) ? 2 : 3;
        const float* bbp[4] = {b1, b2, b3, b4};
        B64[c] = bbp[ti][c - off[ti]];
    }
    if (idx >= 64 * 5120) return;
    int c = idx / 5120, k = idx % 5120;
    int ti = (c < 17) ? 0 : (c < 26) ? 1 : (c < 51) ? 2 : 3;
    const float* Ws[4] = {W1, W2, W3, W4};
    int tag = c - off[ti];
    float v;
    if (k < 4096) {
        int i = k >> 10, kk = k & 1023;
        v = (i == ti) ? Ws[ti][(size_t)kk * tg[ti] + tag] : 0.f;
    } else {
        int kk = k - 4096;
        v = Ws[ti][(size_t)(1024 + kk) * tg[ti] + tag];
    }
    WBT[(size_t)c * 5120 + k] = f2b(v);
}

// ---------------------------------------------------------------------------
// K4: chunk pre-GEMM (unchanged, correctness-verified in round 2).
// ---------------------------------------------------------------------------
__global__ __launch_bounds__(256) void k_pregemm(
    const u16* __restrict__ XB, const u16* __restrict__ WT,
    const float* __restrict__ bfw, const float* __restrict__ bbw,
    const int* __restrict__ lens, u16* __restrict__ P, int t0, int chunk)
{
    int nt = blockIdx.x, mt = blockIdx.y, d = blockIdx.z;
    int s = d >> 1, isbw = d & 1;
    int tid = threadIdx.x, w = tid >> 6, lane = tid & 63, quad = lane >> 4, l15 = lane & 15;
    int mh = w & 1, nh = w >> 1;
    __shared__ u16 lA[128 * 64];
    __shared__ u16 lB[128 * 64];
    const float* bias = (isbw ? bbw : bfw) + (size_t)s * 2048;

    f32x4 acc[4][4];
#pragma unroll
    for (int mi = 0; mi < 4; mi++)
#pragma unroll
        for (int ni = 0; ni < 4; ni++) acc[mi][ni] = fzero();

    for (int kk0 = 0; kk0 < 512; kk0 += 64) {
#pragma unroll
        for (int p = 0; p < 4; p++) {
            int g = p * 256 + tid;
            int row = g >> 3, c16 = g & 7;
            int grow = mt * 128 + row, ttl = grow >> 5, b = grow & 31;
            int t = t0 + ttl, srcT = t;
            if (isbw) { int lb = lens[b]; srcT = (t < lb) ? (lb - 1 - t) : t; }
            const u16* ga = XB + ((size_t)b * TT + srcT) * DD + kk0 + c16 * 8;
            ((uint4*)lA)[g] = *(const uint4*)ga;
            int nrow = nt * 128 + row;
            const u16* gb = WT + ((size_t)d * 2048 + nrow) * 1024 + kk0 + c16 * 8;
            ((uint4*)lB)[g] = *(const uint4*)gb;
        }
        __syncthreads();
#pragma unroll
        for (int ks = 0; ks < 2; ks++) {
            short8 af[4], bf[4];
#pragma unroll
            for (int mi = 0; mi < 4; mi++)
                af[mi] = *(const short8*)(lA + (mh * 64 + mi * 16 + l15) * 64 + ks * 32 + quad * 8);
#pragma unroll
            for (int ni = 0; ni < 4; ni++)
                bf[ni] = *(const short8*)(lB + (nh * 64 + ni * 16 + l15) * 64 + ks * 32 + quad * 8);
#pragma unroll
            for (int mi = 0; mi < 4; mi++)
#pragma unroll
                for (int ni = 0; ni < 4; ni++)
                    acc[mi][ni] = __builtin_amdgcn_mfma_f32_16x16x32_bf16(af[mi], bf[ni], acc[mi][ni], 0, 0, 0);
        }
        __syncthreads();
    }
#pragma unroll
    for (int ni = 0; ni < 4; ni++) {
        int n = nt * 128 + nh * 64 + ni * 16 + l15;
        float bv = bias[n];
#pragma unroll
        for (int mi = 0; mi < 4; mi++) {
#pragma unroll
            for (int r = 0; r < 4; r++) {
                int mlocal = mh * 64 + mi * 16 + quad * 4 + r;
                int grow = mt * 128 + mlocal, ttl = grow >> 5, b = grow & 31;
                P[(((size_t)d * chunk + ttl) * BB + b) * FOURH + n] = f2b(acc[mi][ni][r] + bv);
            }
        }
    }
}

// ---------------------------------------------------------------------------
// K5: PERSISTENT recurrent kernel: `chunk` timesteps per launch.
// 160 WGs = 10 dirs x 16 WGs; 1 WG/CU (149.5 KB dynamic LDS) -> all resident.
// Weights LDS-resident; h exchanged via global + per-dir atomic barrier;
// c & h_prev in epilogue registers (loaded/stored at chunk boundaries).
// ---------------------------------------------------------------------------
__global__ __launch_bounds__(512) void k_rec(
    const u16* __restrict__ WT, const u16* __restrict__ P,
    u16* __restrict__ Hbuf, float* __restrict__ Cst, u16* __restrict__ OUTS,
    const int* __restrict__ lens, unsigned* __restrict__ ctr,
    int t0, int chunk)
{
    extern __shared__ char smem[];
    u16* lW = (u16*)smem;                             // 128 rows x LWPITCH
    float* red = (float*)(smem + 128 * LWPITCH * 2);  // [mtile2][nhalf2][g4][r4][64]

    int blk = blockIdx.x, d = blk >> 4, jj = blk & 15;
    int s = d >> 1, isbw = d & 1;
    int tid = threadIdx.x, w = tid >> 6, lane = tid & 63, quad = lane >> 4, l15 = lane & 15;
    int mtile = w & 1, nhalf = (w >> 1) & 1, khalf = w >> 2;

    // ---- stage recurrent W slice into LDS (once per launch) ----
#pragma unroll
    for (int it = 0; it < 16; ++it) {
        int g16 = it * 512 + tid;          // 8192 granules of 16B
        int row = g16 >> 6, c = g16 & 63;
        int n = (row >> 5) * 512 + jj * 32 + (row & 31);
        const u16* src = WT + ((size_t)d * 2048 + n) * 1024 + 512 + c * 8;
        *(uint4*)(lW + row * LWPITCH + c * 8) = *(const uint4*)src;
    }

    // ---- epilogue lane state (khalf==0 waves own (b,u) cells) ----
    int ug = jj * 32 + nhalf * 16 + l15;     // global unit index
    float c_reg[4], hprev[4];
    int lb_r[4];
    if (khalf == 0) {
#pragma unroll
        for (int r = 0; r < 4; r++) {
            int b = mtile * 16 + quad * 4 + r;
            lb_r[r] = lens[b];
            c_reg[r] = Cst[((size_t)d * BB + b) * HH + ug];
            hprev[r] = b2f(Hbuf[(size_t)(t0 & 1) * HSZ + (size_t)d * BB * HH + (size_t)b * HH + ug]);
        }
    }
    __syncthreads();

    for (int tt = 0; tt < chunk; ++tt) {
        int t = t0 + tt;
        const u16* hin = Hbuf + (size_t)(t & 1) * HSZ + (size_t)d * BB * HH;
        u16* hout      = Hbuf + (size_t)((t + 1) & 1) * HSZ + (size_t)d * BB * HH;

        // prefetch this step's P values early (independent of barrier)
        float pz[4][4];
        if (khalf == 0) {
#pragma unroll
            for (int r = 0; r < 4; r++) {
                int b = mtile * 16 + quad * 4 + r;
                size_t pbase = (((size_t)d * chunk + tt) * BB + b) * FOURH + ug;
#pragma unroll
                for (int g = 0; g < 4; g++) pz[g][r] = b2f(P[pbase + g * 512]);
            }
        }

        f32x4 acc[4];
#pragma unroll
        for (int g = 0; g < 4; g++) acc[g] = fzero();

#pragma unroll
        for (int ks = 0; ks < 8; ks++) {
            int k0 = khalf * 256 + ks * 32;
            short8 a = *(const short8*)(hin + (size_t)(mtile * 16 + l15) * HH + k0 + quad * 8);
#pragma unroll
            for (int g = 0; g < 4; g++) {
                short8 bf = *(const short8*)(lW + (g * 32 + nhalf * 16 + l15) * LWPITCH + k0 + quad * 8);
                acc[g] = __builtin_amdgcn_mfma_f32_16x16x32_bf16(a, bf, acc[g], 0, 0, 0);
            }
        }

        if (khalf == 1) {
#pragma unroll
            for (int g = 0; g < 4; g++)
#pragma unroll
                for (int r = 0; r < 4; r++)
                    red[((((size_t)mtile * 2 + nhalf) * 4 + g) * 4 + r) * 64 + lane] = acc[g][r];
        }
        __syncthreads();
        if (khalf == 0) {
#pragma unroll
            for (int g = 0; g < 4; g++)
#pragma unroll
                for (int r = 0; r < 4; r++)
                    acc[g][r] += red[((((size_t)mtile * 2 + nhalf) * 4 + g) * 4 + r) * 64 + lane];

#pragma unroll
            for (int r = 0; r < 4; r++) {
                int b = mtile * 16 + quad * 4 + r;
                int lb = lb_r[r];
                float zi = acc[0][r] + pz[0][r];
                float zj = acc[1][r] + pz[1][r];
                float zf = acc[2][r] + pz[2][r];
                float zo = acc[3][r] + pz[3][r];
                float cn = sigm(zf + 1.f) * c_reg[r] + sigm(zi) * tanh_(zj);
                float hn = sigm(zo) * tanh_(cn);
                bool act = t < lb;
                if (act) c_reg[r] = cn;
                u16 hv = f2b(act ? hn : hprev[r]);
                hprev[r] = b2f(hv);
                hout[(size_t)b * HH + ug] = hv;
                int twr = isbw ? (act ? (lb - 1 - t) : t) : t;
                OUTS[(((size_t)s * BB + b) * TT + twr) * 1024 + isbw * 512 + ug] = f2b(act ? hn : 0.f);
            }
        }

        // ---- per-dir barrier: h_{t+1} must be LLC-visible to the dir's 16 WGs ----
        __syncthreads();                       // s_barrier implies vmcnt(0): stores at least in L2
        if (tid == 0) {
            __threadfence();                   // release: L2 write-back to coherent point
            atomicAdd(ctr + d * 16, 1u);       // 64B-padded counter per dir
            unsigned target = 16u * (unsigned)(t + 1);
            while (__hip_atomic_load(ctr + d * 16, __ATOMIC_RELAXED, __HIP_MEMORY_SCOPE_AGENT) < target)
                __builtin_amdgcn_s_sleep(1);
            __threadfence();                   // acquire: invalidate L1/L2 before re-reading h
        }
        __syncthreads();
    }

    if (khalf == 0) {
#pragma unroll
        for (int r = 0; r < 4; r++) {
            int b = mtile * 16 + quad * 4 + r;
            Cst[((size_t)d * BB + b) * HH + ug] = c_reg[r];
        }
    }
}

// ---------------------------------------------------------------------------
// K6: heads. logits[16384, 64] = U[16384, 5120] @ WBT^T + B64.
// ---------------------------------------------------------------------------
__global__ __launch_bounds__(256) void k_head(
    const u16* __restrict__ OUTS, const u16* __restrict__ WBT,
    const float* __restrict__ B64, float* __restrict__ OUT)
{
    int tid = threadIdx.x, w = tid >> 6, lane = tid & 63, quad = lane >> 4, l15 = lane & 15;
    int mtile = blockIdx.x * 4 + w, r0 = mtile * 16;
    int row_a = r0 + l15, ba = row_a >> 9, ta = row_a & 511;
    f32x4 acc[4];
#pragma unroll
    for (int ni = 0; ni < 4; ni++) acc[ni] = fzero();

    for (int k0 = 0; k0 < 5120; k0 += 32) {
        int kidx = k0 + quad * 8;
        int blkk = kidx >> 10, kk = kidx & 1023;
        short8 a = *(const short8*)(OUTS + (((size_t)blkk * BB + ba) * TT + ta) * 1024 + kk);
#pragma unroll
        for (int ni = 0; ni < 4; ni++) {
            short8 bf = *(const short8*)(WBT + (size_t)(ni * 16 + l15) * 5120 + kidx);
            acc[ni] = __builtin_amdgcn_mfma_f32_16x16x32_bf16(a, bf, acc[ni], 0, 0, 0);
        }
    }
#pragma unroll
    for (int ni = 0; ni < 4; ni++) {
        int c = ni * 16 + l15;
        float bv = B64[c];
#pragma unroll
        for (int r = 0; r < 4; r++) {
            int row = r0 + quad * 4 + r;
            OUT[(size_t)row * 64 + c] = acc[ni][r] + bv;
        }
    }
}

// ---------------------------------------------------------------------------
extern "C" void kernel_launch(void* const* d_in, const int* in_sizes, int n_in,
                              void* d_out, int out_size, void* d_ws, size_t ws_size,
                              hipStream_t stream) {
    const float* X   = (const float*)d_in[0];
    const int* lens  = (const int*)d_in[1];
    const float* Wf  = (const float*)d_in[2];
    const float* bf_ = (const float*)d_in[3];
    const float* Wb  = (const float*)d_in[4];
    const float* bb_ = (const float*)d_in[5];
    const float* W1  = (const float*)d_in[6];
    const float* b1  = (const float*)d_in[7];
    const float* W2  = (const float*)d_in[8];
    const float* b2  = (const float*)d_in[9];
    const float* W3  = (const float*)d_in[10];
    const float* b3  = (const float*)d_in[11];
    const float* W4  = (const float*)d_in[12];
    const float* b4  = (const float*)d_in[13];

    // ---- runtime workspace layout (never assume ws_size) ----
    char* ws = (char*)d_ws;
    size_t off = 0;
    auto take = [&](size_t bytes) { size_t o = off; off += (bytes + 255) & ~(size_t)255; return o; };
    size_t wtOff   = take((size_t)DIRS * 2048 * 1024 * 2);
    size_t xbOff   = take((size_t)BB * TT * DD * 2);
    size_t outsOff = take((size_t)5 * BB * TT * 1024 * 2);
    size_t hOff    = take((size_t)2 * HSZ * 2);
    size_t cOff    = take((size_t)HSZ * 4);
    size_t ctrOff  = take((size_t)DIRS * 16 * 4);      // 64B-padded per-dir counters
    size_t wbtOff  = take((size_t)64 * 5120 * 2);
    size_t b64Off  = take((size_t)64 * 4);
    (void)cOff; (void)b64Off;
    // elastic P chunk buffer: largest CHUNK in {512..8} that fits
    int chunk = 8;
    for (int c = 512; c >= 8; c >>= 1) {
        size_t pbytes = (size_t)DIRS * c * BB * FOURH * 2;
        if (off + pbytes <= ws_size) { chunk = c; break; }
    }
    size_t pOff = off;

    u16* WT    = (u16*)(ws + wtOff);
    u16* XB    = (u16*)(ws + xbOff);
    u16* P     = (u16*)(ws + pOff);
    u16* OUTS  = (u16*)(ws + outsOff);
    u16* Hbuf  = (u16*)(ws + hOff);
    float* Cst = (float*)(ws + cOff);
    unsigned* CTR = (unsigned*)(ws + ctrOff);
    u16* WBT   = (u16*)(ws + wbtOff);
    float* B64 = (float*)(ws + b64Off);

    // ROUND-3 BUG FIX: zero the ENTIRE [H | C | CTR] span. Previous code zeroed
    // only 256 of the 640 counter bytes -> dirs 4-9 spun on 0xAAAAAAAA counters
    // (always >= target) -> no barrier -> stale-h races -> absmax 9.2e-2.
    hipMemsetAsync(ws + hOff, 0, wbtOff - hOff, stream);

    // allow 149.5 KB dynamic LDS for the persistent kernel (capture-safe host call)
    (void)hipFuncSetAttribute((const void*)k_rec,
                              hipFuncAttributeMaxDynamicSharedMemorySize, SMEM_REC);

    k_convx<<<8192, 256, 0, stream>>>(X, XB);
    k_wt<<<dim3(32, 64, 10), 256, 0, stream>>>(Wf, Wb, WT);
    k_wbt<<<1280, 256, 0, stream>>>(W1, W2, W3, W4, b1, b2, b3, b4, WBT, B64);

    int nchunk = TT / chunk;
    for (int ch = 0; ch < nchunk; ch++) {
        k_pregemm<<<dim3(16, chunk / 4, 10), 256, 0, stream>>>(XB, WT, bf_, bb_, lens, P, ch * chunk, chunk);
        k_rec<<<160, 512, SMEM_REC, stream>>>(WT, P, Hbuf, Cst, OUTS, lens, CTR, ch * chunk, chunk);
    }
    k_head<<<256, 256, 0, stream>>>(OUTS, WBT, B64, (float*)d_out);
}

// Round 5
// 7152.998 us; speedup vs baseline: 1.2045x; 1.2045x over previous
//
#include <hip/hip_runtime.h>
#include <cstdint>
#include <cstddef>

// ---------------------------------------------------------------------------
// Problem constants
// ---------------------------------------------------------------------------
#define BB 32      // batch
#define TT 512     // seq len
#define DD 512     // emb dim
#define HH 512     // lstm size
#define FOURH 2048
#define DIRS 10    // 5 stacks x {fw,bw}
#define HSZ ((size_t)DIRS * BB * HH)     // elems per h ping-pong buffer

typedef unsigned short u16;
typedef __attribute__((ext_vector_type(8))) short short8;   // 8 x bf16 (4 VGPRs)
typedef __attribute__((ext_vector_type(4))) float f32x4;    // MFMA accum

__device__ __forceinline__ u16 f2b(float f) {
    union { float f; unsigned u; } v; v.f = f;
    unsigned u = v.u;
    u = (u + 0x7FFFu + ((u >> 16) & 1u)) >> 16;   // RNE
    return (u16)u;
}
__device__ __forceinline__ float b2f(u16 b) {
    union { unsigned u; float f; } v; v.u = ((unsigned)b) << 16;
    return v.f;
}
__device__ __forceinline__ float sigm(float x) { return 1.f / (1.f + __expf(-x)); }
__device__ __forceinline__ float tanh_(float x) { return 1.f - 2.f / (1.f + __expf(2.f * x)); }
__device__ __forceinline__ f32x4 fzero() { f32x4 z = {0.f, 0.f, 0.f, 0.f}; return z; }

// ---------------------------------------------------------------------------
// K1: x fp32 -> bf16
// ---------------------------------------------------------------------------
__global__ void k_convx(const float* __restrict__ X, u16* __restrict__ XB) {
    int i = blockIdx.x * 256 + threadIdx.x;
    if (i >= (BB * TT * DD) / 4) return;
    float4 v = ((const float4*)X)[i];
    unsigned lo = (unsigned)f2b(v.x) | ((unsigned)f2b(v.y) << 16);
    unsigned hi = (unsigned)f2b(v.z) | ((unsigned)f2b(v.w) << 16);
    uint2 o; o.x = lo; o.y = hi;
    ((uint2*)XB)[i] = o;
}

// ---------------------------------------------------------------------------
// K2: build WT[d][n][k] = W_src[s][k][n] (bf16), LDS-tiled transpose.
// ---------------------------------------------------------------------------
__global__ void k_wt(const float* __restrict__ Wf, const float* __restrict__ Wb,
                     u16* __restrict__ WT) {
    int d = blockIdx.z, s = d >> 1;
    const float* src = (d & 1) ? Wb : Wf;   // [5][1024][2048]
    __shared__ float tile[32][33];
    int tx = threadIdx.x & 31, ty = threadIdx.x >> 5;
    int kt = blockIdx.x, nt = blockIdx.y;
#pragma unroll
    for (int r = 0; r < 4; r++) {
        int k = kt * 32 + ty + r * 8, n = nt * 32 + tx;
        tile[ty + r * 8][tx] = src[((size_t)s * 1024 + k) * 2048 + n];
    }
    __syncthreads();
#pragma unroll
    for (int r = 0; r < 4; r++) {
        int n = nt * 32 + ty + r * 8, k = kt * 32 + tx;
        WT[((size_t)d * 2048 + n) * 1024 + k] = f2b(tile[tx][ty + r * 8]);
    }
}

// ---------------------------------------------------------------------------
// K3: build head weight WBT[64 c][5120 k] bf16 + bias B64[64].
// ---------------------------------------------------------------------------
__global__ void k_wbt(const float* W1, const float* W2, const float* W3, const float* W4,
                      const float* b1, const float* b2, const float* b3, const float* b4,
                      u16* __restrict__ WBT, float* __restrict__ B64) {
    int idx = blockIdx.x * 256 + threadIdx.x;
    const int off[4] = {0, 17, 26, 51};
    const int tg[4]  = {17, 9, 25, 13};
    if (idx < 64) {
        int c = idx;
        int ti = (c < 17) ? 0 : (c < 26) ? 1 : (c < 51) ? 2 : 3;
        const float* bbp[4] = {b1, b2, b3, b4};
        B64[c] = bbp[ti][c - off[ti]];
    }
    if (idx >= 64 * 5120) return;
    int c = idx / 5120, k = idx % 5120;
    int ti = (c < 17) ? 0 : (c < 26) ? 1 : (c < 51) ? 2 : 3;
    const float* Ws[4] = {W1, W2, W3, W4};
    int tag = c - off[ti];
    float v;
    if (k < 4096) {
        int i = k >> 10, kk = k & 1023;
        v = (i == ti) ? Ws[ti][(size_t)kk * tg[ti] + tag] : 0.f;
    } else {
        int kk = k - 4096;
        v = Ws[ti][(size_t)(1024 + kk) * tg[ti] + tag];
    }
    WBT[(size_t)c * 5120 + k] = f2b(v);
}

// ---------------------------------------------------------------------------
// K4: chunk pre-GEMM (unchanged, correctness-verified).
// ---------------------------------------------------------------------------
__global__ __launch_bounds__(256) void k_pregemm(
    const u16* __restrict__ XB, const u16* __restrict__ WT,
    const float* __restrict__ bfw, const float* __restrict__ bbw,
    const int* __restrict__ lens, u16* __restrict__ P, int t0, int chunk)
{
    int nt = blockIdx.x, mt = blockIdx.y, d = blockIdx.z;
    int s = d >> 1, isbw = d & 1;
    int tid = threadIdx.x, w = tid >> 6, lane = tid & 63, quad = lane >> 4, l15 = lane & 15;
    int mh = w & 1, nh = w >> 1;
    __shared__ u16 lA[128 * 64];
    __shared__ u16 lB[128 * 64];
    const float* bias = (isbw ? bbw : bfw) + (size_t)s * 2048;

    f32x4 acc[4][4];
#pragma unroll
    for (int mi = 0; mi < 4; mi++)
#pragma unroll
        for (int ni = 0; ni < 4; ni++) acc[mi][ni] = fzero();

    for (int kk0 = 0; kk0 < 512; kk0 += 64) {
#pragma unroll
        for (int p = 0; p < 4; p++) {
            int g = p * 256 + tid;
            int row = g >> 3, c16 = g & 7;
            int grow = mt * 128 + row, ttl = grow >> 5, b = grow & 31;
            int t = t0 + ttl, srcT = t;
            if (isbw) { int lb = lens[b]; srcT = (t < lb) ? (lb - 1 - t) : t; }
            const u16* ga = XB + ((size_t)b * TT + srcT) * DD + kk0 + c16 * 8;
            ((uint4*)lA)[g] = *(const uint4*)ga;
            int nrow = nt * 128 + row;
            const u16* gb = WT + ((size_t)d * 2048 + nrow) * 1024 + kk0 + c16 * 8;
            ((uint4*)lB)[g] = *(const uint4*)gb;
        }
        __syncthreads();
#pragma unroll
        for (int ks = 0; ks < 2; ks++) {
            short8 af[4], bf[4];
#pragma unroll
            for (int mi = 0; mi < 4; mi++)
                af[mi] = *(const short8*)(lA + (mh * 64 + mi * 16 + l15) * 64 + ks * 32 + quad * 8);
#pragma unroll
            for (int ni = 0; ni < 4; ni++)
                bf[ni] = *(const short8*)(lB + (nh * 64 + ni * 16 + l15) * 64 + ks * 32 + quad * 8);
#pragma unroll
            for (int mi = 0; mi < 4; mi++)
#pragma unroll
                for (int ni = 0; ni < 4; ni++)
                    acc[mi][ni] = __builtin_amdgcn_mfma_f32_16x16x32_bf16(af[mi], bf[ni], acc[mi][ni], 0, 0, 0);
        }
        __syncthreads();
    }
#pragma unroll
    for (int ni = 0; ni < 4; ni++) {
        int n = nt * 128 + nh * 64 + ni * 16 + l15;
        float bv = bias[n];
#pragma unroll
        for (int mi = 0; mi < 4; mi++) {
#pragma unroll
            for (int r = 0; r < 4; r++) {
                int mlocal = mh * 64 + mi * 16 + quad * 4 + r;
                int grow = mt * 128 + mlocal, ttl = grow >> 5, b = grow & 31;
                P[(((size_t)d * chunk + ttl) * BB + b) * FOURH + n] = f2b(acc[mi][ni][r] + bv);
            }
        }
    }
}

// ---------------------------------------------------------------------------
// K5: PERSISTENT recurrent kernel, round-5 rewrite.
//  - Recurrent weights: persistent in VGPRs (32 x short8 = 128 VGPRs/wave),
//    loaded from global WT once per launch. No LDS weight staging.
//  - h exchange: relaxed AGENT-scope atomic loads/stores (sc0 sc1 -> LLC,
//    bypass L1/L2). NO __threadfence in the step loop (round-4 killer: the
//    per-step agent fences = L2 writeback+invalidate per CU per step).
//  - barrier: syncthreads (drains vmcnt) -> atomicAdd -> relaxed poll.
// ---------------------------------------------------------------------------
__global__ __launch_bounds__(512, 2) void k_rec(
    const u16* __restrict__ WT, const u16* __restrict__ P,
    u16* __restrict__ Hbuf, float* __restrict__ Cst, u16* __restrict__ OUTS,
    const int* __restrict__ lens, unsigned* __restrict__ ctr,
    int t0, int chunk)
{
    __shared__ float red[2][2][4][4][64];   // 16 KB reduction buffer

    int blk = blockIdx.x, d = blk >> 4, jj = blk & 15;
    int s = d >> 1, isbw = d & 1;
    int tid = threadIdx.x, w = tid >> 6, lane = tid & 63, quad = lane >> 4, l15 = lane & 15;
    int mtile = w & 1, nhalf = (w >> 1) & 1, khalf = w >> 2;

    // ---- recurrent W fragments: persistent in registers ----
    short8 Bf[8][4];
#pragma unroll
    for (int ks = 0; ks < 8; ks++) {
        int k0 = khalf * 256 + ks * 32;
#pragma unroll
        for (int g = 0; g < 4; g++) {
            int n = g * 512 + jj * 32 + nhalf * 16 + l15;
            Bf[ks][g] = *(const short8*)(WT + ((size_t)d * 2048 + n) * 1024 + 512 + k0 + quad * 8);
        }
    }

    // ---- epilogue lane state (khalf==0 waves own (b,u) cells) ----
    int ug = jj * 32 + nhalf * 16 + l15;     // global unit index
    float c_reg[4], hprev[4];
    int lb_r[4];
    if (khalf == 0) {
#pragma unroll
        for (int r = 0; r < 4; r++) {
            int b = mtile * 16 + quad * 4 + r;
            lb_r[r] = lens[b];
            c_reg[r] = Cst[((size_t)d * BB + b) * HH + ug];
            hprev[r] = b2f(Hbuf[(size_t)(t0 & 1) * HSZ + (size_t)d * BB * HH + (size_t)b * HH + ug]);
        }
    }

    for (int tt = 0; tt < chunk; ++tt) {
        int t = t0 + tt;
        const u16* hin = Hbuf + (size_t)(t & 1) * HSZ + (size_t)d * BB * HH;
        u16* hout      = Hbuf + (size_t)((t + 1) & 1) * HSZ + (size_t)d * BB * HH;

        // prefetch this step's P values (plain cached loads; L2 stays warm now)
        float pz[4][4];
        if (khalf == 0) {
#pragma unroll
            for (int r = 0; r < 4; r++) {
                int b = mtile * 16 + quad * 4 + r;
                size_t pbase = (((size_t)d * chunk + tt) * BB + b) * FOURH + ug;
#pragma unroll
                for (int g = 0; g < 4; g++) pz[g][r] = b2f(P[pbase + g * 512]);
            }
        }

        // ---- coherent A-fragment loads: batched, read LLC directly ----
        uint4 araw[8];
#pragma unroll
        for (int ks = 0; ks < 8; ks++) {
            const unsigned* ap = (const unsigned*)(hin + (size_t)(mtile * 16 + l15) * HH
                                                   + khalf * 256 + ks * 32 + quad * 8);
            araw[ks].x = __hip_atomic_load(ap + 0, __ATOMIC_RELAXED, __HIP_MEMORY_SCOPE_AGENT);
            araw[ks].y = __hip_atomic_load(ap + 1, __ATOMIC_RELAXED, __HIP_MEMORY_SCOPE_AGENT);
            araw[ks].z = __hip_atomic_load(ap + 2, __ATOMIC_RELAXED, __HIP_MEMORY_SCOPE_AGENT);
            araw[ks].w = __hip_atomic_load(ap + 3, __ATOMIC_RELAXED, __HIP_MEMORY_SCOPE_AGENT);
        }

        f32x4 acc[4];
#pragma unroll
        for (int g = 0; g < 4; g++) acc[g] = fzero();
#pragma unroll
        for (int ks = 0; ks < 8; ks++) {
            short8 a = *(const short8*)(&araw[ks]);
#pragma unroll
            for (int g = 0; g < 4; g++)
                acc[g] = __builtin_amdgcn_mfma_f32_16x16x32_bf16(a, Bf[ks][g], acc[g], 0, 0, 0);
        }

        if (khalf == 1) {
#pragma unroll
            for (int g = 0; g < 4; g++)
#pragma unroll
                for (int r = 0; r < 4; r++) red[mtile][nhalf][g][r][lane] = acc[g][r];
        }
        __syncthreads();
        if (khalf == 0) {
#pragma unroll
            for (int g = 0; g < 4; g++)
#pragma unroll
                for (int r = 0; r < 4; r++) acc[g][r] += red[mtile][nhalf][g][r][lane];

#pragma unroll
            for (int r = 0; r < 4; r++) {
                int b = mtile * 16 + quad * 4 + r;
                int lb = lb_r[r];
                float zi = acc[0][r] + pz[0][r];
                float zj = acc[1][r] + pz[1][r];
                float zf = acc[2][r] + pz[2][r];
                float zo = acc[3][r] + pz[3][r];
                float cn = sigm(zf + 1.f) * c_reg[r] + sigm(zi) * tanh_(zj);
                float hn = sigm(zo) * tanh_(cn);
                bool act = t < lb;
                if (act) c_reg[r] = cn;
                u16 hv = f2b(act ? hn : hprev[r]);
                hprev[r] = b2f(hv);
                // coherent h store -> LLC (visible to sibling WGs, no fence)
                __hip_atomic_store(&hout[(size_t)b * HH + ug], hv,
                                   __ATOMIC_RELAXED, __HIP_MEMORY_SCOPE_AGENT);
                int twr = isbw ? (act ? (lb - 1 - t) : t) : t;   // fused reverse scatter
                OUTS[(((size_t)s * BB + b) * TT + twr) * 1024 + isbw * 512 + ug] = f2b(act ? hn : 0.f);
            }
        }

        // ---- per-dir barrier (no cache fences: h traffic is already coherent) ----
        __syncthreads();                       // implies s_waitcnt vmcnt(0): h stores at LLC
        if (tid == 0) {
            atomicAdd(ctr + d * 16, 1u);       // device-scope, 64B-padded per dir
            unsigned target = 16u * (unsigned)(t + 1);
            while (__hip_atomic_load(ctr + d * 16, __ATOMIC_RELAXED, __HIP_MEMORY_SCOPE_AGENT) < target)
                __builtin_amdgcn_s_sleep(1);
        }
        __syncthreads();
    }

    if (khalf == 0) {
#pragma unroll
        for (int r = 0; r < 4; r++) {
            int b = mtile * 16 + quad * 4 + r;
            Cst[((size_t)d * BB + b) * HH + ug] = c_reg[r];
        }
    }
}

// ---------------------------------------------------------------------------
// K6: heads. logits[16384, 64] = U[16384, 5120] @ WBT^T + B64.
// ---------------------------------------------------------------------------
__global__ __launch_bounds__(256) void k_head(
    const u16* __restrict__ OUTS, const u16* __restrict__ WBT,
    const float* __restrict__ B64, float* __restrict__ OUT)
{
    int tid = threadIdx.x, w = tid >> 6, lane = tid & 63, quad = lane >> 4, l15 = lane & 15;
    int mtile = blockIdx.x * 4 + w, r0 = mtile * 16;
    int row_a = r0 + l15, ba = row_a >> 9, ta = row_a & 511;
    f32x4 acc[4];
#pragma unroll
    for (int ni = 0; ni < 4; ni++) acc[ni] = fzero();

    for (int k0 = 0; k0 < 5120; k0 += 32) {
        int kidx = k0 + quad * 8;
        int blkk = kidx >> 10, kk = kidx & 1023;
        short8 a = *(const short8*)(OUTS + (((size_t)blkk * BB + ba) * TT + ta) * 1024 + kk);
#pragma unroll
        for (int ni = 0; ni < 4; ni++) {
            short8 bf = *(const short8*)(WBT + (size_t)(ni * 16 + l15) * 5120 + kidx);
            acc[ni] = __builtin_amdgcn_mfma_f32_16x16x32_bf16(a, bf, acc[ni], 0, 0, 0);
        }
    }
#pragma unroll
    for (int ni = 0; ni < 4; ni++) {
        int c = ni * 16 + l15;
        float bv = B64[c];
#pragma unroll
        for (int r = 0; r < 4; r++) {
            int row = r0 + quad * 4 + r;
            OUT[(size_t)row * 64 + c] = acc[ni][r] + bv;
        }
    }
}

// ---------------------------------------------------------------------------
extern "C" void kernel_launch(void* const* d_in, const int* in_sizes, int n_in,
                              void* d_out, int out_size, void* d_ws, size_t ws_size,
                              hipStream_t stream) {
    const float* X   = (const float*)d_in[0];
    const int* lens  = (const int*)d_in[1];
    const float* Wf  = (const float*)d_in[2];
    const float* bf_ = (const float*)d_in[3];
    const float* Wb  = (const float*)d_in[4];
    const float* bb_ = (const float*)d_in[5];
    const float* W1  = (const float*)d_in[6];
    const float* b1  = (const float*)d_in[7];
    const float* W2  = (const float*)d_in[8];
    const float* b2  = (const float*)d_in[9];
    const float* W3  = (const float*)d_in[10];
    const float* b3  = (const float*)d_in[11];
    const float* W4  = (const float*)d_in[12];
    const float* b4  = (const float*)d_in[13];

    // ---- runtime workspace layout (never assume ws_size) ----
    char* ws = (char*)d_ws;
    size_t off = 0;
    auto take = [&](size_t bytes) { size_t o = off; off += (bytes + 255) & ~(size_t)255; return o; };
    size_t wtOff   = take((size_t)DIRS * 2048 * 1024 * 2);
    size_t xbOff   = take((size_t)BB * TT * DD * 2);
    size_t outsOff = take((size_t)5 * BB * TT * 1024 * 2);
    size_t hOff    = take((size_t)2 * HSZ * 2);
    size_t cOff    = take((size_t)HSZ * 4);
    size_t ctrOff  = take((size_t)DIRS * 16 * 4);      // 64B-padded per-dir counters
    size_t wbtOff  = take((size_t)64 * 5120 * 2);
    size_t b64Off  = take((size_t)64 * 4);
    // elastic P chunk buffer: largest CHUNK in {512..8} that fits
    int chunk = 8;
    for (int c = 512; c >= 8; c >>= 1) {
        size_t pbytes = (size_t)DIRS * c * BB * FOURH * 2;
        if (off + pbytes <= ws_size) { chunk = c; break; }
    }
    size_t pOff = off;

    u16* WT    = (u16*)(ws + wtOff);
    u16* XB    = (u16*)(ws + xbOff);
    u16* P     = (u16*)(ws + pOff);
    u16* OUTS  = (u16*)(ws + outsOff);
    u16* Hbuf  = (u16*)(ws + hOff);
    float* Cst = (float*)(ws + cOff);
    unsigned* CTR = (unsigned*)(ws + ctrOff);
    u16* WBT   = (u16*)(ws + wbtOff);
    float* B64 = (float*)(ws + b64Off);

    // zero the ENTIRE [H | C | CTR] span (round-3 lesson: short memset = race)
    hipMemsetAsync(ws + hOff, 0, wbtOff - hOff, stream);

    k_convx<<<8192, 256, 0, stream>>>(X, XB);
    k_wt<<<dim3(32, 64, 10), 256, 0, stream>>>(Wf, Wb, WT);
    k_wbt<<<1280, 256, 0, stream>>>(W1, W2, W3, W4, b1, b2, b3, b4, WBT, B64);

    int nchunk = TT / chunk;
    for (int ch = 0; ch < nchunk; ch++) {
        k_pregemm<<<dim3(16, chunk / 4, 10), 256, 0, stream>>>(XB, WT, bf_, bb_, lens, P, ch * chunk, chunk);
        k_rec<<<160, 512, 0, stream>>>(WT, P, Hbuf, Cst, OUTS, lens, CTR, ch * chunk, chunk);
    }
    k_head<<<256, 256, 0, stream>>>(OUTS, WBT, B64, (float*)d_out);
}

// Round 6
// 6168.975 us; speedup vs baseline: 1.3966x; 1.1595x over previous
//
#include <hip/hip_runtime.h>
#include <cstdint>
#include <cstddef>

// ---------------------------------------------------------------------------
// Problem constants
// ---------------------------------------------------------------------------
#define BB 32      // batch
#define TT 512     // seq len
#define DD 512     // emb dim
#define HH 512     // lstm size
#define FOURH 2048
#define DIRS 10    // 5 stacks x {fw,bw}
#define HSZ ((size_t)DIRS * BB * HH)     // elems per h ping-pong buffer
#define LWPITCH 520                      // 512 + 8 pad: l15 stride 260 words = bank+4 -> ~2-way
#define SMEM_REC (128 * LWPITCH * 2 + 2 * 2 * 4 * 4 * 64 * 4)   // 133120 + 16384 = 149504

typedef unsigned short u16;
typedef __attribute__((ext_vector_type(8))) short short8;   // 8 x bf16 (4 VGPRs)
typedef __attribute__((ext_vector_type(4))) float f32x4;    // MFMA accum

__device__ __forceinline__ u16 f2b(float f) {
    union { float f; unsigned u; } v; v.f = f;
    unsigned u = v.u;
    u = (u + 0x7FFFu + ((u >> 16) & 1u)) >> 16;   // RNE
    return (u16)u;
}
__device__ __forceinline__ float b2f(u16 b) {
    union { unsigned u; float f; } v; v.u = ((unsigned)b) << 16;
    return v.f;
}
__device__ __forceinline__ float sigm(float x) { return 1.f / (1.f + __expf(-x)); }
__device__ __forceinline__ float tanh_(float x) { return 1.f - 2.f / (1.f + __expf(2.f * x)); }
__device__ __forceinline__ f32x4 fzero() { f32x4 z = {0.f, 0.f, 0.f, 0.f}; return z; }

// ---------------------------------------------------------------------------
// K1: x fp32 -> bf16
// ---------------------------------------------------------------------------
__global__ void k_convx(const float* __restrict__ X, u16* __restrict__ XB) {
    int i = blockIdx.x * 256 + threadIdx.x;
    if (i >= (BB * TT * DD) / 4) return;
    float4 v = ((const float4*)X)[i];
    unsigned lo = (unsigned)f2b(v.x) | ((unsigned)f2b(v.y) << 16);
    unsigned hi = (unsigned)f2b(v.z) | ((unsigned)f2b(v.w) << 16);
    uint2 o; o.x = lo; o.y = hi;
    ((uint2*)XB)[i] = o;
}

// ---------------------------------------------------------------------------
// K2: build WT[d][n][k] = W_src[s][k][n] (bf16), LDS-tiled transpose.
// ---------------------------------------------------------------------------
__global__ void k_wt(const float* __restrict__ Wf, const float* __restrict__ Wb,
                     u16* __restrict__ WT) {
    int d = blockIdx.z, s = d >> 1;
    const float* src = (d & 1) ? Wb : Wf;   // [5][1024][2048]
    __shared__ float tile[32][33];
    int tx = threadIdx.x & 31, ty = threadIdx.x >> 5;
    int kt = blockIdx.x, nt = blockIdx.y;
#pragma unroll
    for (int r = 0; r < 4; r++) {
        int k = kt * 32 + ty + r * 8, n = nt * 32 + tx;
        tile[ty + r * 8][tx] = src[((size_t)s * 1024 + k) * 2048 + n];
    }
    __syncthreads();
#pragma unroll
    for (int r = 0; r < 4; r++) {
        int n = nt * 32 + ty + r * 8, k = kt * 32 + tx;
        WT[((size_t)d * 2048 + n) * 1024 + k] = f2b(tile[tx][ty + r * 8]);
    }
}

// ---------------------------------------------------------------------------
// K3: build head weight WBT[64 c][5120 k] bf16 + bias B64[64].
// ---------------------------------------------------------------------------
__global__ void k_wbt(const float* W1, const float* W2, const float* W3, const float* W4,
                      const float* b1, const float* b2, const float* b3, const float* b4,
                      u16* __restrict__ WBT, float* __restrict__ B64) {
    int idx = blockIdx.x * 256 + threadIdx.x;
    const int off[4] = {0, 17, 26, 51};
    const int tg[4]  = {17, 9, 25, 13};
    if (idx < 64) {
        int c = idx;
        int ti = (c < 17) ? 0 : (c < 26) ? 1 : (c < 51) ? 2 : 3;
        const float* bbp[4] = {b1, b2, b3, b4};
        B64[c] = bbp[ti][c - off[ti]];
    }
    if (idx >= 64 * 5120) return;
    int c = idx / 5120, k = idx % 5120;
    int ti = (c < 17) ? 0 : (c < 26) ? 1 : (c < 51) ? 2 : 3;
    const float* Ws[4] = {W1, W2, W3, W4};
    int tag = c - off[ti];
    float v;
    if (k < 4096) {
        int i = k >> 10, kk = k & 1023;
        v = (i == ti) ? Ws[ti][(size_t)kk * tg[ti] + tag] : 0.f;
    } else {
        int kk = k - 4096;
        v = Ws[ti][(size_t)(1024 + kk) * tg[ti] + tag];
    }
    WBT[(size_t)c * 5120 + k] = f2b(v);
}

// ---------------------------------------------------------------------------
// K5: SINGLE persistent kernel for ALL 512 timesteps, x-GEMM fused.
//   - W_h (recurrent): register/AGPR-resident fragments (proven round 5).
//   - W_x (input): this WG's 128x512 slice LDS-resident (133 KB, loaded once).
//   - No P buffer at all: z = x_t@Wx + h@Wh + bias computed per step.
//   - h exchange: relaxed agent-scope atomics -> LLC, no fences (round 5).
//   - HBM traffic: WT 40 MB + XB once; per-step traffic is LLC/LDS only.
// ---------------------------------------------------------------------------
__global__ __launch_bounds__(512, 2) void k_rec(
    const u16* __restrict__ WT, const u16* __restrict__ XB,
    const float* __restrict__ bfw, const float* __restrict__ bbw,
    u16* __restrict__ Hbuf, float* __restrict__ Cst, u16* __restrict__ OUTS,
    const int* __restrict__ lens, unsigned* __restrict__ ctr)
{
    extern __shared__ char smem[];
    u16* lWx = (u16*)smem;                             // [128][LWPITCH] bf16
    float* red = (float*)(smem + 128 * LWPITCH * 2);   // [2][2][4][4][64]

    int blk = blockIdx.x, d = blk >> 4, jj = blk & 15;
    int s = d >> 1, isbw = d & 1;
    int tid = threadIdx.x, w = tid >> 6, lane = tid & 63, quad = lane >> 4, l15 = lane & 15;
    int mtile = w & 1, nhalf = (w >> 1) & 1, khalf = w >> 2;

    // ---- stage W_x slice into LDS (once): row g*32+u32 <- WT[d][g*512+jj*32+u32][k 0..511]
#pragma unroll
    for (int it = 0; it < 16; ++it) {
        int g16 = it * 512 + tid;          // 8192 granules of 16B
        int row = g16 >> 6, c = g16 & 63;
        int n = (row >> 5) * 512 + jj * 32 + (row & 31);
        const u16* src = WT + ((size_t)d * 2048 + n) * 1024 + c * 8;   // x half: k in [0,512)
        *(uint4*)(lWx + row * LWPITCH + c * 8) = *(const uint4*)src;
    }

    // ---- W_h fragments: persistent registers/AGPRs ----
    short8 Bf[8][4];
#pragma unroll
    for (int ks = 0; ks < 8; ks++) {
        int k0 = khalf * 256 + ks * 32;
#pragma unroll
        for (int g = 0; g < 4; g++) {
            int n = g * 512 + jj * 32 + nhalf * 16 + l15;
            Bf[ks][g] = *(const short8*)(WT + ((size_t)d * 2048 + n) * 1024 + 512 + k0 + quad * 8);
        }
    }

    // ---- per-lane persistent state ----
    int bA = mtile * 16 + l15;             // A-fragment row (batch index) for this lane
    int lbA = lens[bA];                    // for x-gather
    int ug = jj * 32 + nhalf * 16 + l15;   // global unit index (epilogue lanes)
    const float* bias = (isbw ? bbw : bfw) + (size_t)s * 2048;
    float c_reg[4], hprev[4], bv_r[4];
    int lb_r[4];
    if (khalf == 0) {
#pragma unroll
        for (int g = 0; g < 4; g++) bv_r[g] = bias[g * 512 + ug];
#pragma unroll
        for (int r = 0; r < 4; r++) {
            int b = mtile * 16 + quad * 4 + r;
            lb_r[r] = lens[b];
            c_reg[r] = Cst[((size_t)d * BB + b) * HH + ug];
            hprev[r] = b2f(Hbuf[(size_t)d * BB * HH + (size_t)b * HH + ug]);  // t0=0, buf 0
        }
    }
    __syncthreads();   // lWx ready

    for (int t = 0; t < TT; ++t) {
        const u16* hin = Hbuf + (size_t)(t & 1) * HSZ + (size_t)d * BB * HH;
        u16* hout      = Hbuf + (size_t)((t + 1) & 1) * HSZ + (size_t)d * BB * HH;

        // ---- A_x loads (plain cached; XB is read-only and LLC/L2-resident) ----
        int srcT = isbw ? ((t < lbA) ? (lbA - 1 - t) : t) : t;
        const u16* xrow = XB + ((size_t)bA * TT + srcT) * DD + khalf * 256;
        uint4 xraw[8];
#pragma unroll
        for (int ks = 0; ks < 8; ks++)
            xraw[ks] = *(const uint4*)(xrow + ks * 32 + quad * 8);

        // ---- A_h coherent loads (LLC, no fence needed) ----
        uint4 araw[8];
#pragma unroll
        for (int ks = 0; ks < 8; ks++) {
            const unsigned* ap = (const unsigned*)(hin + (size_t)bA * HH
                                                   + khalf * 256 + ks * 32 + quad * 8);
            araw[ks].x = __hip_atomic_load(ap + 0, __ATOMIC_RELAXED, __HIP_MEMORY_SCOPE_AGENT);
            araw[ks].y = __hip_atomic_load(ap + 1, __ATOMIC_RELAXED, __HIP_MEMORY_SCOPE_AGENT);
            araw[ks].z = __hip_atomic_load(ap + 2, __ATOMIC_RELAXED, __HIP_MEMORY_SCOPE_AGENT);
            araw[ks].w = __hip_atomic_load(ap + 3, __ATOMIC_RELAXED, __HIP_MEMORY_SCOPE_AGENT);
        }

        f32x4 acc[4];
#pragma unroll
        for (int g = 0; g < 4; g++) acc[g] = fzero();

        // ---- x-GEMM from LDS weights ----
#pragma unroll
        for (int ks = 0; ks < 8; ks++) {
            short8 a = *(const short8*)(&xraw[ks]);
#pragma unroll
            for (int g = 0; g < 4; g++) {
                short8 bfr = *(const short8*)(lWx + (g * 32 + nhalf * 16 + l15) * LWPITCH
                                              + khalf * 256 + ks * 32 + quad * 8);
                acc[g] = __builtin_amdgcn_mfma_f32_16x16x32_bf16(a, bfr, acc[g], 0, 0, 0);
            }
        }
        // ---- h-GEMM from register weights ----
#pragma unroll
        for (int ks = 0; ks < 8; ks++) {
            short8 a = *(const short8*)(&araw[ks]);
#pragma unroll
            for (int g = 0; g < 4; g++)
                acc[g] = __builtin_amdgcn_mfma_f32_16x16x32_bf16(a, Bf[ks][g], acc[g], 0, 0, 0);
        }

        if (khalf == 1) {
#pragma unroll
            for (int g = 0; g < 4; g++)
#pragma unroll
                for (int r = 0; r < 4; r++)
                    red[((((size_t)mtile * 2 + nhalf) * 4 + g) * 4 + r) * 64 + lane] = acc[g][r];
        }
        __syncthreads();
        if (khalf == 0) {
#pragma unroll
            for (int g = 0; g < 4; g++)
#pragma unroll
                for (int r = 0; r < 4; r++)
                    acc[g][r] += red[((((size_t)mtile * 2 + nhalf) * 4 + g) * 4 + r) * 64 + lane];

#pragma unroll
            for (int r = 0; r < 4; r++) {
                int b = mtile * 16 + quad * 4 + r;
                int lb = lb_r[r];
                float zi = acc[0][r] + bv_r[0];
                float zj = acc[1][r] + bv_r[1];
                float zf = acc[2][r] + bv_r[2];
                float zo = acc[3][r] + bv_r[3];
                float cn = sigm(zf + 1.f) * c_reg[r] + sigm(zi) * tanh_(zj);
                float hn = sigm(zo) * tanh_(cn);
                bool act = t < lb;
                if (act) c_reg[r] = cn;
                u16 hv = f2b(act ? hn : hprev[r]);
                hprev[r] = b2f(hv);
                __hip_atomic_store(&hout[(size_t)b * HH + ug], hv,
                                   __ATOMIC_RELAXED, __HIP_MEMORY_SCOPE_AGENT);
                int twr = isbw ? (act ? (lb - 1 - t) : t) : t;   // fused reverse scatter
                OUTS[(((size_t)s * BB + b) * TT + twr) * 1024 + isbw * 512 + ug] = f2b(act ? hn : 0.f);
            }
        }

        // ---- per-dir barrier (h already coherent; syncthreads drains stores) ----
        __syncthreads();
        if (tid == 0) {
            atomicAdd(ctr + d * 16, 1u);
            unsigned target = 16u * (unsigned)(t + 1);
            while (__hip_atomic_load(ctr + d * 16, __ATOMIC_RELAXED, __HIP_MEMORY_SCOPE_AGENT) < target)
                __builtin_amdgcn_s_sleep(1);
        }
        __syncthreads();
    }
}

// ---------------------------------------------------------------------------
// K6: heads. logits[16384, 64] = U[16384, 5120] @ WBT^T + B64.
// ---------------------------------------------------------------------------
__global__ __launch_bounds__(256) void k_head(
    const u16* __restrict__ OUTS, const u16* __restrict__ WBT,
    const float* __restrict__ B64, float* __restrict__ OUT)
{
    int tid = threadIdx.x, w = tid >> 6, lane = tid & 63, quad = lane >> 4, l15 = lane & 15;
    int mtile = blockIdx.x * 4 + w, r0 = mtile * 16;
    int row_a = r0 + l15, ba = row_a >> 9, ta = row_a & 511;
    f32x4 acc[4];
#pragma unroll
    for (int ni = 0; ni < 4; ni++) acc[ni] = fzero();

    for (int k0 = 0; k0 < 5120; k0 += 32) {
        int kidx = k0 + quad * 8;
        int blkk = kidx >> 10, kk = kidx & 1023;
        short8 a = *(const short8*)(OUTS + (((size_t)blkk * BB + ba) * TT + ta) * 1024 + kk);
#pragma unroll
        for (int ni = 0; ni < 4; ni++) {
            short8 bf = *(const short8*)(WBT + (size_t)(ni * 16 + l15) * 5120 + kidx);
            acc[ni] = __builtin_amdgcn_mfma_f32_16x16x32_bf16(a, bf, acc[ni], 0, 0, 0);
        }
    }
#pragma unroll
    for (int ni = 0; ni < 4; ni++) {
        int c = ni * 16 + l15;
        float bv = B64[c];
#pragma unroll
        for (int r = 0; r < 4; r++) {
            int row = r0 + quad * 4 + r;
            OUT[(size_t)row * 64 + c] = acc[ni][r] + bv;
        }
    }
}

// ---------------------------------------------------------------------------
extern "C" void kernel_launch(void* const* d_in, const int* in_sizes, int n_in,
                              void* d_out, int out_size, void* d_ws, size_t ws_size,
                              hipStream_t stream) {
    const float* X   = (const float*)d_in[0];
    const int* lens  = (const int*)d_in[1];
    const float* Wf  = (const float*)d_in[2];
    const float* bf_ = (const float*)d_in[3];
    const float* Wb  = (const float*)d_in[4];
    const float* bb_ = (const float*)d_in[5];
    const float* W1  = (const float*)d_in[6];
    const float* b1  = (const float*)d_in[7];
    const float* W2  = (const float*)d_in[8];
    const float* b2  = (const float*)d_in[9];
    const float* W3  = (const float*)d_in[10];
    const float* b3  = (const float*)d_in[11];
    const float* W4  = (const float*)d_in[12];
    const float* b4  = (const float*)d_in[13];

    // ---- runtime workspace layout (no P buffer anymore; ~226 MB total) ----
    char* ws = (char*)d_ws;
    size_t off = 0;
    auto take = [&](size_t bytes) { size_t o = off; off += (bytes + 255) & ~(size_t)255; return o; };
    size_t wtOff   = take((size_t)DIRS * 2048 * 1024 * 2);
    size_t xbOff   = take((size_t)BB * TT * DD * 2);
    size_t outsOff = take((size_t)5 * BB * TT * 1024 * 2);
    size_t hOff    = take((size_t)2 * HSZ * 2);
    size_t cOff    = take((size_t)HSZ * 4);
    size_t ctrOff  = take((size_t)DIRS * 16 * 4);      // 64B-padded per-dir counters
    size_t wbtOff  = take((size_t)64 * 5120 * 2);
    size_t b64Off  = take((size_t)64 * 4);
    (void)ctrOff;

    u16* WT    = (u16*)(ws + wtOff);
    u16* XB    = (u16*)(ws + xbOff);
    u16* OUTS  = (u16*)(ws + outsOff);
    u16* Hbuf  = (u16*)(ws + hOff);
    float* Cst = (float*)(ws + cOff);
    unsigned* CTR = (unsigned*)(ws + ctrOff);
    u16* WBT   = (u16*)(ws + wbtOff);
    float* B64 = (float*)(ws + b64Off);

    // zero the ENTIRE [H | C | CTR] span (round-3 lesson: short memset = race)
    hipMemsetAsync(ws + hOff, 0, wbtOff - hOff, stream);

    // 149.5 KB dynamic LDS for the persistent kernel (worked in rounds 3-4)
    (void)hipFuncSetAttribute((const void*)k_rec,
                              hipFuncAttributeMaxDynamicSharedMemorySize, SMEM_REC);

    k_convx<<<8192, 256, 0, stream>>>(X, XB);
    k_wt<<<dim3(32, 64, 10), 256, 0, stream>>>(Wf, Wb, WT);
    k_wbt<<<1280, 256, 0, stream>>>(W1, W2, W3, W4, b1, b2, b3, b4, WBT, B64);

    // one persistent dispatch for all 512 timesteps
    k_rec<<<160, 512, SMEM_REC, stream>>>(WT, XB, bf_, bb_, Hbuf, Cst, OUTS, lens, CTR);

    k_head<<<256, 256, 0, stream>>>(OUTS, WBT, B64, (float*)d_out);
}

// Round 7
// 3766.052 us; speedup vs baseline: 2.2878x; 1.6380x over previous
//
#include <hip/hip_runtime.h>
#include <cstdint>
#include <cstddef>

// ---------------------------------------------------------------------------
// Problem constants
// ---------------------------------------------------------------------------
#define BB 32      // batch
#define TT 512     // seq len
#define DD 512     // emb dim
#define HH 512     // lstm size
#define FOURH 2048
#define DIRS 10    // 5 stacks x {fw,bw}
#define HSZ ((size_t)DIRS * BB * HH)     // elems per h ping-pong buffer
#define LWPITCH 520                      // 512 + 8 pad (16B-aligned rows, 2-way max on b128)
#define SMEM_REC (128 * LWPITCH * 2 + 2 * 2 * 4 * 4 * 64 * 4)   // 133120 + 16384 = 149504

typedef unsigned short u16;
typedef __attribute__((ext_vector_type(8))) short short8;   // 8 x bf16 (4 VGPRs)
typedef __attribute__((ext_vector_type(4))) float f32x4;    // MFMA accum

__device__ __forceinline__ u16 f2b(float f) {
    union { float f; unsigned u; } v; v.f = f;
    unsigned u = v.u;
    u = (u + 0x7FFFu + ((u >> 16) & 1u)) >> 16;   // RNE
    return (u16)u;
}
__device__ __forceinline__ float b2f(u16 b) {
    union { unsigned u; float f; } v; v.u = ((unsigned)b) << 16;
    return v.f;
}
__device__ __forceinline__ float sigm(float x) { return 1.f / (1.f + __expf(-x)); }
__device__ __forceinline__ float tanh_(float x) { return 1.f - 2.f / (1.f + __expf(2.f * x)); }
__device__ __forceinline__ f32x4 fzero() { f32x4 z = {0.f, 0.f, 0.f, 0.f}; return z; }

// Coherent 16B load: bypasses L1/L2 (sc0 sc1 -> LLC, the agent coherence point)
// but is a NORMAL vmcnt-tracked vector load -> many outstanding, one RTT for all.
// (Round 5/6 used per-dword relaxed atomic loads here: 32 serial LLC RTTs/wave
//  ~= the measured 11 us/step floor.)
__device__ __forceinline__ uint4 load_coh16(const u16* p) {
    uint4 r;
    asm volatile("global_load_dwordx4 %0, %1, off sc0 sc1"
                 : "=v"(r) : "v"(p) : "memory");
    return r;
}

// ---------------------------------------------------------------------------
// K1: x fp32 -> bf16
// ---------------------------------------------------------------------------
__global__ void k_convx(const float* __restrict__ X, u16* __restrict__ XB) {
    int i = blockIdx.x * 256 + threadIdx.x;
    if (i >= (BB * TT * DD) / 4) return;
    float4 v = ((const float4*)X)[i];
    unsigned lo = (unsigned)f2b(v.x) | ((unsigned)f2b(v.y) << 16);
    unsigned hi = (unsigned)f2b(v.z) | ((unsigned)f2b(v.w) << 16);
    uint2 o; o.x = lo; o.y = hi;
    ((uint2*)XB)[i] = o;
}

// ---------------------------------------------------------------------------
// K2: build WT[d][n][k] = W_src[s][k][n] (bf16), LDS-tiled transpose.
// ---------------------------------------------------------------------------
__global__ void k_wt(const float* __restrict__ Wf, const float* __restrict__ Wb,
                     u16* __restrict__ WT) {
    int d = blockIdx.z, s = d >> 1;
    const float* src = (d & 1) ? Wb : Wf;   // [5][1024][2048]
    __shared__ float tile[32][33];
    int tx = threadIdx.x & 31, ty = threadIdx.x >> 5;
    int kt = blockIdx.x, nt = blockIdx.y;
#pragma unroll
    for (int r = 0; r < 4; r++) {
        int k = kt * 32 + ty + r * 8, n = nt * 32 + tx;
        tile[ty + r * 8][tx] = src[((size_t)s * 1024 + k) * 2048 + n];
    }
    __syncthreads();
#pragma unroll
    for (int r = 0; r < 4; r++) {
        int n = nt * 32 + ty + r * 8, k = kt * 32 + tx;
        WT[((size_t)d * 2048 + n) * 1024 + k] = f2b(tile[tx][ty + r * 8]);
    }
}

// ---------------------------------------------------------------------------
// K3: build head weight WBT[64 c][5120 k] bf16 + bias B64[64].
// ---------------------------------------------------------------------------
__global__ void k_wbt(const float* W1, const float* W2, const float* W3, const float* W4,
                      const float* b1, const float* b2, const float* b3, const float* b4,
                      u16* __restrict__ WBT, float* __restrict__ B64) {
    int idx = blockIdx.x * 256 + threadIdx.x;
    const int off[4] = {0, 17, 26, 51};
    const int tg[4]  = {17, 9, 25, 13};
    if (idx < 64) {
        int c = idx;
        int ti = (c < 17) ? 0 : (c < 26) ? 1 : (c < 51) ? 2 : 3;
        const float* bbp[4] = {b1, b2, b3, b4};
        B64[c] = bbp[ti][c - off[ti]];
    }
    if (idx >= 64 * 5120) return;
    int c = idx / 5120, k = idx % 5120;
    int ti = (c < 17) ? 0 : (c < 26) ? 1 : (c < 51) ? 2 : 3;
    const float* Ws[4] = {W1, W2, W3, W4};
    int tag = c - off[ti];
    float v;
    if (k < 4096) {
        int i = k >> 10, kk = k & 1023;
        v = (i == ti) ? Ws[ti][(size_t)kk * tg[ti] + tag] : 0.f;
    } else {
        int kk = k - 4096;
        v = Ws[ti][(size_t)(1024 + kk) * tg[ti] + tag];
    }
    WBT[(size_t)c * 5120 + k] = f2b(v);
}

// ---------------------------------------------------------------------------
// K5: SINGLE persistent kernel for ALL 512 timesteps, x-GEMM fused.
//   - W_h: register/AGPR-resident. W_x: LDS-resident (133 KB). No P buffer.
//   - h exchange: sc0/sc1 stores (atomic relaxed) + PIPELINED sc0/sc1 asm
//     loads (round-7 change; was per-dword atomic loads = serial RTT floor).
//   - per-dir barrier: atomicAdd + relaxed poll, no fences.
// ---------------------------------------------------------------------------
__global__ __launch_bounds__(512, 2) void k_rec(
    const u16* __restrict__ WT, const u16* __restrict__ XB,
    const float* __restrict__ bfw, const float* __restrict__ bbw,
    u16* __restrict__ Hbuf, float* __restrict__ Cst, u16* __restrict__ OUTS,
    const int* __restrict__ lens, unsigned* __restrict__ ctr)
{
    extern __shared__ char smem[];
    u16* lWx = (u16*)smem;                             // [128][LWPITCH] bf16
    float* red = (float*)(smem + 128 * LWPITCH * 2);   // [2][2][4][4][64]

    int blk = blockIdx.x, d = blk >> 4, jj = blk & 15;
    int s = d >> 1, isbw = d & 1;
    int tid = threadIdx.x, w = tid >> 6, lane = tid & 63, quad = lane >> 4, l15 = lane & 15;
    int mtile = w & 1, nhalf = (w >> 1) & 1, khalf = w >> 2;

    // ---- stage W_x slice into LDS (once) ----
#pragma unroll
    for (int it = 0; it < 16; ++it) {
        int g16 = it * 512 + tid;          // 8192 granules of 16B
        int row = g16 >> 6, c = g16 & 63;
        int n = (row >> 5) * 512 + jj * 32 + (row & 31);
        const u16* src = WT + ((size_t)d * 2048 + n) * 1024 + c * 8;   // x half: k in [0,512)
        *(uint4*)(lWx + row * LWPITCH + c * 8) = *(const uint4*)src;
    }

    // ---- W_h fragments: persistent registers/AGPRs ----
    short8 Bf[8][4];
#pragma unroll
    for (int ks = 0; ks < 8; ks++) {
        int k0 = khalf * 256 + ks * 32;
#pragma unroll
        for (int g = 0; g < 4; g++) {
            int n = g * 512 + jj * 32 + nhalf * 16 + l15;
            Bf[ks][g] = *(const short8*)(WT + ((size_t)d * 2048 + n) * 1024 + 512 + k0 + quad * 8);
        }
    }

    // ---- per-lane persistent state ----
    int bA = mtile * 16 + l15;             // A-fragment row (batch index)
    int lbA = lens[bA];
    int ug = jj * 32 + nhalf * 16 + l15;   // global unit index (epilogue lanes)
    const float* bias = (isbw ? bbw : bfw) + (size_t)s * 2048;
    float c_reg[4], hprev[4], bv_r[4];
    int lb_r[4];
    if (khalf == 0) {
#pragma unroll
        for (int g = 0; g < 4; g++) bv_r[g] = bias[g * 512 + ug];
#pragma unroll
        for (int r = 0; r < 4; r++) {
            int b = mtile * 16 + quad * 4 + r;
            lb_r[r] = lens[b];
            c_reg[r] = Cst[((size_t)d * BB + b) * HH + ug];
            hprev[r] = b2f(Hbuf[(size_t)d * BB * HH + (size_t)b * HH + ug]);  // t0=0, buf 0
        }
    }
    __syncthreads();   // lWx ready

    for (int t = 0; t < TT; ++t) {
        const u16* hin = Hbuf + (size_t)(t & 1) * HSZ + (size_t)d * BB * HH;
        u16* hout      = Hbuf + (size_t)((t + 1) & 1) * HSZ + (size_t)d * BB * HH;

        // ---- A_x loads (plain cached, pipelined) ----
        int srcT = isbw ? ((t < lbA) ? (lbA - 1 - t) : t) : t;
        const u16* xrow = XB + ((size_t)bA * TT + srcT) * DD + khalf * 256;
        uint4 xraw[8];
#pragma unroll
        for (int ks = 0; ks < 8; ks++)
            xraw[ks] = *(const uint4*)(xrow + ks * 32 + quad * 8);

        // ---- A_h coherent loads: ISSUE ALL 8, no wait (one LLC RTT total) ----
        uint4 araw[8];
#pragma unroll
        for (int ks = 0; ks < 8; ks++)
            araw[ks] = load_coh16(hin + (size_t)bA * HH + khalf * 256 + ks * 32 + quad * 8);

        f32x4 acc[4];
#pragma unroll
        for (int g = 0; g < 4; g++) acc[g] = fzero();

        // ---- x-GEMM from LDS weights (hides the h-load LLC RTT) ----
#pragma unroll
        for (int ks = 0; ks < 8; ks++) {
            short8 a = *(const short8*)(&xraw[ks]);
#pragma unroll
            for (int g = 0; g < 4; g++) {
                short8 bfr = *(const short8*)(lWx + (g * 32 + nhalf * 16 + l15) * LWPITCH
                                              + khalf * 256 + ks * 32 + quad * 8);
                acc[g] = __builtin_amdgcn_mfma_f32_16x16x32_bf16(a, bfr, acc[g], 0, 0, 0);
            }
        }

        // drain the asm h loads (not compiler-tracked), then h-GEMM
        asm volatile("s_waitcnt vmcnt(0)" ::: "memory");
#pragma unroll
        for (int ks = 0; ks < 8; ks++) {
            short8 a = *(const short8*)(&araw[ks]);
#pragma unroll
            for (int g = 0; g < 4; g++)
                acc[g] = __builtin_amdgcn_mfma_f32_16x16x32_bf16(a, Bf[ks][g], acc[g], 0, 0, 0);
        }

        if (khalf == 1) {
#pragma unroll
            for (int g = 0; g < 4; g++)
#pragma unroll
                for (int r = 0; r < 4; r++)
                    red[((((size_t)mtile * 2 + nhalf) * 4 + g) * 4 + r) * 64 + lane] = acc[g][r];
        }
        __syncthreads();
        if (khalf == 0) {
#pragma unroll
            for (int g = 0; g < 4; g++)
#pragma unroll
                for (int r = 0; r < 4; r++)
                    acc[g][r] += red[((((size_t)mtile * 2 + nhalf) * 4 + g) * 4 + r) * 64 + lane];

#pragma unroll
            for (int r = 0; r < 4; r++) {
                int b = mtile * 16 + quad * 4 + r;
                int lb = lb_r[r];
                float zi = acc[0][r] + bv_r[0];
                float zj = acc[1][r] + bv_r[1];
                float zf = acc[2][r] + bv_r[2];
                float zo = acc[3][r] + bv_r[3];
                float cn = sigm(zf + 1.f) * c_reg[r] + sigm(zi) * tanh_(zj);
                float hn = sigm(zo) * tanh_(cn);
                bool act = t < lb;
                if (act) c_reg[r] = cn;
                u16 hv = f2b(act ? hn : hprev[r]);
                hprev[r] = b2f(hv);
                __hip_atomic_store(&hout[(size_t)b * HH + ug], hv,
                                   __ATOMIC_RELAXED, __HIP_MEMORY_SCOPE_AGENT);
                int twr = isbw ? (act ? (lb - 1 - t) : t) : t;   // fused reverse scatter
                OUTS[(((size_t)s * BB + b) * TT + twr) * 1024 + isbw * 512 + ug] = f2b(act ? hn : 0.f);
            }
        }

        // ---- per-dir barrier (h already coherent; syncthreads drains stores) ----
        __syncthreads();
        if (tid == 0) {
            atomicAdd(ctr + d * 16, 1u);
            unsigned target = 16u * (unsigned)(t + 1);
            while (__hip_atomic_load(ctr + d * 16, __ATOMIC_RELAXED, __HIP_MEMORY_SCOPE_AGENT) < target)
                __builtin_amdgcn_s_sleep(1);
        }
        __syncthreads();
    }
}

// ---------------------------------------------------------------------------
// K6: heads. logits[16384, 64] = U[16384, 5120] @ WBT^T + B64.
// ---------------------------------------------------------------------------
__global__ __launch_bounds__(256) void k_head(
    const u16* __restrict__ OUTS, const u16* __restrict__ WBT,
    const float* __restrict__ B64, float* __restrict__ OUT)
{
    int tid = threadIdx.x, w = tid >> 6, lane = tid & 63, quad = lane >> 4, l15 = lane & 15;
    int mtile = blockIdx.x * 4 + w, r0 = mtile * 16;
    int row_a = r0 + l15, ba = row_a >> 9, ta = row_a & 511;
    f32x4 acc[4];
#pragma unroll
    for (int ni = 0; ni < 4; ni++) acc[ni] = fzero();

    for (int k0 = 0; k0 < 5120; k0 += 32) {
        int kidx = k0 + quad * 8;
        int blkk = kidx >> 10, kk = kidx & 1023;
        short8 a = *(const short8*)(OUTS + (((size_t)blkk * BB + ba) * TT + ta) * 1024 + kk);
#pragma unroll
        for (int ni = 0; ni < 4; ni++) {
            short8 bf = *(const short8*)(WBT + (size_t)(ni * 16 + l15) * 5120 + kidx);
            acc[ni] = __builtin_amdgcn_mfma_f32_16x16x32_bf16(a, bf, acc[ni], 0, 0, 0);
        }
    }
#pragma unroll
    for (int ni = 0; ni < 4; ni++) {
        int c = ni * 16 + l15;
        float bv = B64[c];
#pragma unroll
        for (int r = 0; r < 4; r++) {
            int row = r0 + quad * 4 + r;
            OUT[(size_t)row * 64 + c] = acc[ni][r] + bv;
        }
    }
}

// ---------------------------------------------------------------------------
extern "C" void kernel_launch(void* const* d_in, const int* in_sizes, int n_in,
                              void* d_out, int out_size, void* d_ws, size_t ws_size,
                              hipStream_t stream) {
    const float* X   = (const float*)d_in[0];
    const int* lens  = (const int*)d_in[1];
    const float* Wf  = (const float*)d_in[2];
    const float* bf_ = (const float*)d_in[3];
    const float* Wb  = (const float*)d_in[4];
    const float* bb_ = (const float*)d_in[5];
    const float* W1  = (const float*)d_in[6];
    const float* b1  = (const float*)d_in[7];
    const float* W2  = (const float*)d_in[8];
    const float* b2  = (const float*)d_in[9];
    const float* W3  = (const float*)d_in[10];
    const float* b3  = (const float*)d_in[11];
    const float* W4  = (const float*)d_in[12];
    const float* b4  = (const float*)d_in[13];

    // ---- runtime workspace layout (~226 MB total) ----
    char* ws = (char*)d_ws;
    size_t off = 0;
    auto take = [&](size_t bytes) { size_t o = off; off += (bytes + 255) & ~(size_t)255; return o; };
    size_t wtOff   = take((size_t)DIRS * 2048 * 1024 * 2);
    size_t xbOff   = take((size_t)BB * TT * DD * 2);
    size_t outsOff = take((size_t)5 * BB * TT * 1024 * 2);
    size_t hOff    = take((size_t)2 * HSZ * 2);
    size_t cOff    = take((size_t)HSZ * 4);
    size_t ctrOff  = take((size_t)DIRS * 16 * 4);      // 64B-padded per-dir counters
    size_t wbtOff  = take((size_t)64 * 5120 * 2);
    size_t b64Off  = take((size_t)64 * 4);

    u16* WT    = (u16*)(ws + wtOff);
    u16* XB    = (u16*)(ws + xbOff);
    u16* OUTS  = (u16*)(ws + outsOff);
    u16* Hbuf  = (u16*)(ws + hOff);
    float* Cst = (float*)(ws + cOff);
    unsigned* CTR = (unsigned*)(ws + ctrOff);
    u16* WBT   = (u16*)(ws + wbtOff);
    float* B64 = (float*)(ws + b64Off);

    // zero the ENTIRE [H | C | CTR] span (round-3 lesson: short memset = race)
    hipMemsetAsync(ws + hOff, 0, wbtOff - hOff, stream);

    // 149.5 KB dynamic LDS for the persistent kernel
    (void)hipFuncSetAttribute((const void*)k_rec,
                              hipFuncAttributeMaxDynamicSharedMemorySize, SMEM_REC);

    k_convx<<<8192, 256, 0, stream>>>(X, XB);
    k_wt<<<dim3(32, 64, 10), 256, 0, stream>>>(Wf, Wb, WT);
    k_wbt<<<1280, 256, 0, stream>>>(W1, W2, W3, W4, b1, b2, b3, b4, WBT, B64);

    // one persistent dispatch for all 512 timesteps
    k_rec<<<160, 512, SMEM_REC, stream>>>(WT, XB, bf_, bb_, Hbuf, Cst, OUTS, lens, CTR);

    k_head<<<256, 256, 0, stream>>>(OUTS, WBT, B64, (float*)d_out);
}